// Round 1
// baseline (357.654 us; speedup 1.0000x reference)
//
#include <hip/hip_runtime.h>
#include <hip/hip_bf16.h>

#define N_PTS  4096
#define M_Q    16384
#define C_IN   256
#define C_SKIP 128
#define C_H    384      // C_IN + C_SKIP
#define HDIM   256
#define NSPLIT 8
#define PTS_PER_SPLIT (N_PTS / NSPLIT)   // 512

__device__ __forceinline__ void insert3(float d, int j,
                                        float& b0, float& b1, float& b2,
                                        int& i0, int& i1, int& i2) {
    if (d < b2) {
        if (d < b1) {
            b2 = b1; i2 = i1;
            if (d < b0) { b1 = b0; i1 = i0; b0 = d; i0 = j; }
            else        { b1 = d;  i1 = j; }
        } else { b2 = d; i2 = j; }
    }
}

// ---- Phase 1: partial kNN, 8-way split of the point set --------------------
__global__ __launch_bounds__(256) void knn_part_kernel(
        const float* __restrict__ pos, const float* __restrict__ pos_skip,
        float* __restrict__ cand_d, int* __restrict__ cand_i) {
    __shared__ float sp[PTS_PER_SPLIT * 3];
    const int s  = blockIdx.y;
    const int q  = blockIdx.x * 256 + threadIdx.x;
    const int j0 = s * PTS_PER_SPLIT;
    for (int i = threadIdx.x; i < PTS_PER_SPLIT * 3; i += 256)
        sp[i] = pos[j0 * 3 + i];
    __syncthreads();
    const float qx = pos_skip[q*3+0], qy = pos_skip[q*3+1], qz = pos_skip[q*3+2];
    float b0 = 3e38f, b1 = 3e38f, b2 = 3e38f;
    int   i0 = 0, i1 = 0, i2 = 0;
    #pragma unroll 4
    for (int j = 0; j < PTS_PER_SPLIT; ++j) {
        float dx = qx - sp[3*j+0];
        float dy = qy - sp[3*j+1];
        float dz = qz - sp[3*j+2];
        float d  = dx*dx + dy*dy + dz*dz;   // exact form == reference's d2k recompute
        insert3(d, j0 + j, b0, b1, b2, i0, i1, i2);
    }
    const int base = (q * NSPLIT + s) * 3;
    cand_d[base+0] = b0; cand_d[base+1] = b1; cand_d[base+2] = b2;
    cand_i[base+0] = i0; cand_i[base+1] = i1; cand_i[base+2] = i2;
}

// ---- Phase 2: merge 24 candidates -> top-3, inverse-distance weights -------
__global__ __launch_bounds__(256) void knn_merge_kernel(
        const float* __restrict__ cand_d, const int* __restrict__ cand_i,
        int* __restrict__ idx, float* __restrict__ wn) {
    const int q = blockIdx.x * 256 + threadIdx.x;
    float b0 = 3e38f, b1 = 3e38f, b2 = 3e38f;
    int   i0 = 0, i1 = 0, i2 = 0;
    #pragma unroll
    for (int c = 0; c < NSPLIT * 3; ++c) {
        float d = cand_d[q * NSPLIT * 3 + c];
        int   j = cand_i[q * NSPLIT * 3 + c];
        insert3(d, j, b0, b1, b2, i0, i1, i2);
    }
    float w0 = 1.0f / fmaxf(b0, 1e-16f);
    float w1 = 1.0f / fmaxf(b1, 1e-16f);
    float w2 = 1.0f / fmaxf(b2, 1e-16f);
    float inv = 1.0f / (w0 + w1 + w2);
    idx[q*3+0] = i0; idx[q*3+1] = i1; idx[q*3+2] = i2;
    wn[q*3+0] = w0 * inv; wn[q*3+1] = w1 * inv; wn[q*3+2] = w2 * inv;
}

// ---- Phase 3: gather-interpolate + concat skip -> h[M x 384] ---------------
__global__ __launch_bounds__(384) void interp_kernel(
        const float* __restrict__ x, const float* __restrict__ x_skip,
        const int* __restrict__ idx, const float* __restrict__ wn,
        float* __restrict__ h) {
    const int q = blockIdx.x;
    const int t = threadIdx.x;
    if (t < C_IN) {
        const int   i0 = idx[q*3+0], i1 = idx[q*3+1], i2 = idx[q*3+2];
        const float w0 = wn[q*3+0],  w1 = wn[q*3+1],  w2 = wn[q*3+2];
        float v = w0 * x[(size_t)i0 * C_IN + t]
                + w1 * x[(size_t)i1 * C_IN + t]
                + w2 * x[(size_t)i2 * C_IN + t];
        h[(size_t)q * C_H + t] = v;
    } else {
        const int c = t - C_IN;
        h[(size_t)q * C_H + C_IN + c] = x_skip[(size_t)q * C_SKIP + c];
    }
}

// ---- Phase 4/5: f32 SIMT GEMM, 128x128x16 tile, 8x8 per thread -------------
// C[M x 256] = A[M x K] @ B[K x 256] + bias, optional relu. ldb = ldc = 256.
template<bool RELU>
__global__ __launch_bounds__(256) void gemm_kernel(
        const float* __restrict__ A, int lda,
        const float* __restrict__ B, const float* __restrict__ bias,
        float* __restrict__ C, int K) {
    __shared__ float As[16][132];   // transposed A tile, padded
    __shared__ float Bs[16][132];
    const int t  = threadIdx.x;
    const int m0 = blockIdx.y * 128;
    const int n0 = blockIdx.x * 128;
    const int tx = t & 15, ty = t >> 4;
    const int rowA = t >> 1,  csA = (t & 1) * 8;
    const int rowB = t >> 4,  csB = (t & 15) * 8;

    float acc[8][8] = {};

    for (int k0 = 0; k0 < K; k0 += 16) {
        const float4 a0 = *(const float4*)(A + (size_t)(m0 + rowA) * lda + k0 + csA);
        const float4 a1 = *(const float4*)(A + (size_t)(m0 + rowA) * lda + k0 + csA + 4);
        const float4 v0 = *(const float4*)(B + (size_t)(k0 + rowB) * 256 + n0 + csB);
        const float4 v1 = *(const float4*)(B + (size_t)(k0 + rowB) * 256 + n0 + csB + 4);
        __syncthreads();   // previous iteration's LDS reads complete
        As[csA+0][rowA] = a0.x; As[csA+1][rowA] = a0.y;
        As[csA+2][rowA] = a0.z; As[csA+3][rowA] = a0.w;
        As[csA+4][rowA] = a1.x; As[csA+5][rowA] = a1.y;
        As[csA+6][rowA] = a1.z; As[csA+7][rowA] = a1.w;
        *(float4*)&Bs[rowB][csB]     = v0;
        *(float4*)&Bs[rowB][csB + 4] = v1;
        __syncthreads();
        #pragma unroll
        for (int kk = 0; kk < 16; ++kk) {
            float a[8], b[8];
            *(float4*)&a[0] = *(const float4*)&As[kk][ty*8];
            *(float4*)&a[4] = *(const float4*)&As[kk][ty*8 + 4];
            *(float4*)&b[0] = *(const float4*)&Bs[kk][tx*8];
            *(float4*)&b[4] = *(const float4*)&Bs[kk][tx*8 + 4];
            #pragma unroll
            for (int i = 0; i < 8; ++i)
                #pragma unroll
                for (int j = 0; j < 8; ++j)
                    acc[i][j] = fmaf(a[i], b[j], acc[i][j]);
        }
    }

    float bv[8];
    *(float4*)&bv[0] = *(const float4*)(bias + n0 + tx*8);
    *(float4*)&bv[4] = *(const float4*)(bias + n0 + tx*8 + 4);
    #pragma unroll
    for (int i = 0; i < 8; ++i) {
        const int m = m0 + ty*8 + i;
        float r[8];
        #pragma unroll
        for (int j = 0; j < 8; ++j) {
            float v = acc[i][j] + bv[j];
            if (RELU) v = fmaxf(v, 0.0f);
            r[j] = v;
        }
        *(float4*)(C + (size_t)m * 256 + n0 + tx*8)     = *(float4*)&r[0];
        *(float4*)(C + (size_t)m * 256 + n0 + tx*8 + 4) = *(float4*)&r[4];
    }
}

// ---- Phase 6: pos_skip passthrough + batch_skip zeros ----------------------
__global__ __launch_bounds__(256) void tail_kernel(
        const float* __restrict__ pos_skip, float* __restrict__ out) {
    const int i = blockIdx.x * 256 + threadIdx.x;
    if (i < M_Q * 3) out[(size_t)M_Q * HDIM + i] = pos_skip[i];
    if (i < M_Q)     out[(size_t)M_Q * HDIM + (size_t)M_Q * 3 + i] = 0.0f;
}

extern "C" void kernel_launch(void* const* d_in, const int* in_sizes, int n_in,
                              void* d_out, int out_size, void* d_ws, size_t ws_size,
                              hipStream_t stream) {
    (void)in_sizes; (void)n_in; (void)out_size; (void)ws_size;
    const float* x        = (const float*)d_in[0];   // [4096,256]
    const float* pos      = (const float*)d_in[1];   // [4096,3]
    const float* x_skip   = (const float*)d_in[3];   // [16384,128]
    const float* pos_skip = (const float*)d_in[4];   // [16384,3]
    const float* W1       = (const float*)d_in[6];   // [384,256]
    const float* b1       = (const float*)d_in[7];   // [256]
    const float* W2       = (const float*)d_in[8];   // [256,256]
    const float* b2       = (const float*)d_in[9];   // [256]
    float* out = (float*)d_out;

    char* ws = (char*)d_ws;
    float* cand_d = (float*)(ws + 0);          // M*24*4   = 1,572,864 B
    int*   cand_i = (int*)  (ws + 1572864);    // M*24*4   = 1,572,864 B
    int*   idx    = (int*)  (ws + 3145728);    // M*3*4    =   196,608 B
    float* wn     = (float*)(ws + 3342336);    // M*3*4    =   196,608 B
    float* h      = (float*)(ws + 3538944);    // M*384*4  = 25,165,824 B
    float* hid    = (float*)(ws + 28704768);   // M*256*4  = 16,777,216 B
                                               // total ~45.5 MB

    knn_part_kernel <<<dim3(M_Q/256, NSPLIT), 256, 0, stream>>>(pos, pos_skip, cand_d, cand_i);
    knn_merge_kernel<<<M_Q/256, 256, 0, stream>>>(cand_d, cand_i, idx, wn);
    interp_kernel   <<<M_Q, C_H, 0, stream>>>(x, x_skip, idx, wn, h);
    gemm_kernel<true> <<<dim3(HDIM/128, M_Q/128), 256, 0, stream>>>(h, C_H, W1, b1, hid, C_H);
    gemm_kernel<false><<<dim3(HDIM/128, M_Q/128), 256, 0, stream>>>(hid, HDIM, W2, b2, out, HDIM);
    tail_kernel     <<<(M_Q*3 + 255)/256, 256, 0, stream>>>(pos_skip, out);
}

// Round 3
// 316.029 us; speedup vs baseline: 1.1317x; 1.1317x over previous
//
#include <hip/hip_runtime.h>
#include <hip/hip_bf16.h>

#define N_PTS  4096
#define M_Q    16384
#define C_IN   256
#define C_SKIP 128
#define C_H    384      // C_IN + C_SKIP
#define HDIM   256
#define NSPLIT 32
#define PTS_PER_SPLIT (N_PTS / NSPLIT)   // 128

typedef __bf16 bf16x8 __attribute__((ext_vector_type(8)));
typedef float  f32x4  __attribute__((ext_vector_type(4)));

__device__ __forceinline__ void insert3(float d, int j,
                                        float& b0, float& b1, float& b2,
                                        int& i0, int& i1, int& i2) {
    if (d < b2) {
        if (d < b1) {
            b2 = b1; i2 = i1;
            if (d < b0) { b1 = b0; i1 = i0; b0 = d; i0 = j; }
            else        { b1 = d;  i1 = j; }
        } else { b2 = d; i2 = j; }
    }
}

// ---- Phase 1: partial kNN, 32-way split, surrogate key d' = |p|^2 - 2 q.p --
__global__ __launch_bounds__(256) void knn_part_kernel(
        const float* __restrict__ pos, const float* __restrict__ pos_skip,
        float* __restrict__ cand_d, int* __restrict__ cand_i) {
    __shared__ float4 sp[PTS_PER_SPLIT];
    const int s  = blockIdx.y;
    const int q  = blockIdx.x * 256 + threadIdx.x;
    const int j0 = s * PTS_PER_SPLIT;
    if (threadIdx.x < PTS_PER_SPLIT) {
        const float px = pos[(j0 + threadIdx.x)*3 + 0];
        const float py = pos[(j0 + threadIdx.x)*3 + 1];
        const float pz = pos[(j0 + threadIdx.x)*3 + 2];
        sp[threadIdx.x] = make_float4(px, py, pz, px*px + py*py + pz*pz);
    }
    __syncthreads();
    const float m2x = -2.0f * pos_skip[q*3+0];
    const float m2y = -2.0f * pos_skip[q*3+1];
    const float m2z = -2.0f * pos_skip[q*3+2];
    float b0 = 3e38f, b1 = 3e38f, b2 = 3e38f;
    int   i0 = 0, i1 = 0, i2 = 0;
    #pragma unroll 8
    for (int j = 0; j < PTS_PER_SPLIT; ++j) {
        const float4 p = sp[j];
        const float d = fmaf(p.x, m2x, fmaf(p.y, m2y, fmaf(p.z, m2z, p.w)));
        insert3(d, j0 + j, b0, b1, b2, i0, i1, i2);
    }
    // layout [s][q][r] -> fully coalesced writes
    const int base = (s * M_Q + q) * 3;
    cand_d[base+0] = b0; cand_d[base+1] = b1; cand_d[base+2] = b2;
    cand_i[base+0] = i0; cand_i[base+1] = i1; cand_i[base+2] = i2;
}

// ---- Phase 2: merge 96 candidates (4 lanes/query) -> top-3 + weights -------
__global__ __launch_bounds__(256) void knn_merge_kernel(
        const float* __restrict__ cand_d, const int* __restrict__ cand_i,
        const float* __restrict__ pos, const float* __restrict__ pos_skip,
        int* __restrict__ idx, float* __restrict__ wn) {
    const int tid = blockIdx.x * 256 + threadIdx.x;
    const int q = tid >> 2;
    const int l = tid & 3;             // 4 lanes per query, lane l owns 8 splits
    float b0 = 3e38f, b1 = 3e38f, b2 = 3e38f;
    int   i0 = 0, i1 = 0, i2 = 0;
    #pragma unroll
    for (int u = 0; u < NSPLIT/4; ++u) {
        const int s = l * (NSPLIT/4) + u;   // ascending split = ascending index, tie-break safe
        const int base = (s * M_Q + q) * 3;
        const float d0 = cand_d[base+0], d1 = cand_d[base+1], d2c = cand_d[base+2];
        const int   j0 = cand_i[base+0], j1 = cand_i[base+1], j2c = cand_i[base+2];
        insert3(d0, j0,  b0,b1,b2, i0,i1,i2);
        insert3(d1, j1,  b0,b1,b2, i0,i1,i2);
        insert3(d2c, j2c, b0,b1,b2, i0,i1,i2);
    }
    // cross-lane merge; lower lane's triple is the base so ties keep lowest index
    #pragma unroll
    for (int m = 1; m <= 2; m <<= 1) {
        const float nb0 = __shfl_xor(b0, m), nb1 = __shfl_xor(b1, m), nb2 = __shfl_xor(b2, m);
        const int   ni0 = __shfl_xor(i0, m), ni1 = __shfl_xor(i1, m), ni2 = __shfl_xor(i2, m);
        const bool upper = (l & m) != 0;
        float e0 = upper ? b0 : nb0, e1 = upper ? b1 : nb1, e2 = upper ? b2 : nb2;
        int   f0 = upper ? i0 : ni0, f1 = upper ? i1 : ni1, f2 = upper ? i2 : ni2;
        if (upper) { b0 = nb0; b1 = nb1; b2 = nb2; i0 = ni0; i1 = ni1; i2 = ni2; }
        insert3(e0, f0, b0,b1,b2, i0,i1,i2);
        insert3(e1, f1, b0,b1,b2, i0,i1,i2);
        insert3(e2, f2, b0,b1,b2, i0,i1,i2);
    }
    if (l == 0) {
        const float qx = pos_skip[q*3+0], qy = pos_skip[q*3+1], qz = pos_skip[q*3+2];
        float w[3]; int ii[3] = {i0, i1, i2};
        #pragma unroll
        for (int r = 0; r < 3; ++r) {
            const float dx = qx - pos[ii[r]*3+0];
            const float dy = qy - pos[ii[r]*3+1];
            const float dz = qz - pos[ii[r]*3+2];
            const float d2 = dx*dx + dy*dy + dz*dz;   // exact recompute, like reference d2k
            w[r] = 1.0f / fmaxf(d2, 1e-16f);
        }
        const float inv = 1.0f / (w[0] + w[1] + w[2]);
        idx[q*3+0] = ii[0]; idx[q*3+1] = ii[1]; idx[q*3+2] = ii[2];
        wn[q*3+0] = w[0]*inv; wn[q*3+1] = w[1]*inv; wn[q*3+2] = w[2]*inv;
    }
}

// ---- Phase 3: gather-interpolate + concat skip -> h[M x 384] (bf16) --------
__global__ __launch_bounds__(192) void interp_kernel(
        const float* __restrict__ x, const float* __restrict__ x_skip,
        const int* __restrict__ idx, const float* __restrict__ wn,
        __hip_bfloat16* __restrict__ h) {
    const int q = blockIdx.x;
    const int t = threadIdx.x;
    if (t < 128) {
        const int c = t * 2;
        const int   i0 = idx[q*3+0], i1 = idx[q*3+1], i2 = idx[q*3+2];
        const float w0 = wn[q*3+0],  w1 = wn[q*3+1],  w2 = wn[q*3+2];
        const float2 v0 = *(const float2*)(x + (size_t)i0 * C_IN + c);
        const float2 v1 = *(const float2*)(x + (size_t)i1 * C_IN + c);
        const float2 v2 = *(const float2*)(x + (size_t)i2 * C_IN + c);
        __hip_bfloat162 o;
        o.x = __float2bfloat16(w0*v0.x + w1*v1.x + w2*v2.x);
        o.y = __float2bfloat16(w0*v0.y + w1*v1.y + w2*v2.y);
        *(__hip_bfloat162*)(h + (size_t)q * C_H + c) = o;
    } else {
        const int c = (t - 128) * 2;
        const float2 v = *(const float2*)(x_skip + (size_t)q * C_SKIP + c);
        __hip_bfloat162 o;
        o.x = __float2bfloat16(v.x);
        o.y = __float2bfloat16(v.y);
        *(__hip_bfloat162*)(h + (size_t)q * C_H + C_IN + c) = o;
    }
}

// ---- Weight convert + transpose: W[k][n] f32 -> Wt[n][k] bf16 --------------
__global__ __launch_bounds__(256) void convert_w_kernel(
        const float* __restrict__ W1, const float* __restrict__ W2,
        __hip_bfloat16* __restrict__ W1t, __hip_bfloat16* __restrict__ W2t) {
    const int i = blockIdx.x * 256 + threadIdx.x;
    if (i < C_H * HDIM) {
        const int k = i / HDIM, n = i % HDIM;
        W1t[n * C_H + k] = __float2bfloat16(W1[i]);
    } else {
        const int j = i - C_H * HDIM;
        const int k = j / HDIM, n = j % HDIM;
        W2t[n * HDIM + k] = __float2bfloat16(W2[j]);
    }
}

// ---- Phase 4/5: bf16 MFMA GEMM. C[M x 256] = A[M x K] @ Bt^T + bias --------
// A[M x K] bf16 row-major, Bt[256 x K] bf16 row-major (pre-transposed weights).
// Block 256 thr = 4 waves (2x2), tile BM=64 x BN=128, BK=32.
// Staging: B tile = 128x32 bf16 = 8 KB -> 256 thr x 32 B (two int4 each).
//          A tile =  64x32 bf16 = 4 KB -> 128 thr x 32 B (two int4 each).
template<bool RELU, int KDIM, typename OUT_T>
__global__ __launch_bounds__(256) void gemm_bf16_kernel(
        const __bf16* __restrict__ A, const __bf16* __restrict__ Bt,
        const float* __restrict__ bias, OUT_T* __restrict__ C) {
    __shared__ __bf16 As[64][40];    // pad 32->40 (80B stride, 16B aligned)
    __shared__ __bf16 Bs[128][40];
    const int t    = threadIdx.x;
    const int wave = t >> 6;
    const int lane = t & 63;
    const int ln = lane & 15, kq = lane >> 4;
    const int m0 = blockIdx.y * 64;
    const int n0 = blockIdx.x * 128;
    const int wm = (wave >> 1) * 32;   // 2 m-tiles of 16
    const int wn = (wave & 1) * 64;    // 4 n-tiles of 16

    const int rA = t >> 1, cA = (t & 1) * 16;   // 16 bf16 (= 32 B) per thread

    f32x4 acc[2][4] = {};

    for (int k0 = 0; k0 < KDIM; k0 += 32) {
        // global loads issued before barrier to overlap prior MFMA
        int4 aval0, aval1;
        if (t < 128) {
            aval0 = *(const int4*)(A + (size_t)(m0 + rA) * KDIM + k0 + cA);
            aval1 = *(const int4*)(A + (size_t)(m0 + rA) * KDIM + k0 + cA + 8);
        }
        const int4 bval0 = *(const int4*)(Bt + (size_t)(n0 + rA) * KDIM + k0 + cA);
        const int4 bval1 = *(const int4*)(Bt + (size_t)(n0 + rA) * KDIM + k0 + cA + 8);
        __syncthreads();   // previous iteration's LDS reads complete
        if (t < 128) {
            *(int4*)&As[rA][cA]     = aval0;
            *(int4*)&As[rA][cA + 8] = aval1;
        }
        *(int4*)&Bs[rA][cA]     = bval0;
        *(int4*)&Bs[rA][cA + 8] = bval1;
        __syncthreads();
        bf16x8 af[2], bf[4];
        #pragma unroll
        for (int mt = 0; mt < 2; ++mt)
            af[mt] = *(const bf16x8*)&As[wm + mt*16 + ln][kq*8];
        #pragma unroll
        for (int nt = 0; nt < 4; ++nt)
            bf[nt] = *(const bf16x8*)&Bs[wn + nt*16 + ln][kq*8];
        #pragma unroll
        for (int mt = 0; mt < 2; ++mt)
            #pragma unroll
            for (int nt = 0; nt < 4; ++nt)
                acc[mt][nt] = __builtin_amdgcn_mfma_f32_16x16x32_bf16(
                                  af[mt], bf[nt], acc[mt][nt], 0, 0, 0);
    }

    // epilogue: C/D layout col=lane&15, row=(lane>>4)*4+reg
    #pragma unroll
    for (int nt = 0; nt < 4; ++nt) {
        const int n = n0 + wn + nt*16 + ln;
        const float bv = bias[n];
        #pragma unroll
        for (int mt = 0; mt < 2; ++mt) {
            const int mbase = m0 + wm + mt*16 + kq*4;
            #pragma unroll
            for (int r = 0; r < 4; ++r) {
                float v = acc[mt][nt][r] + bv;
                if (RELU) v = fmaxf(v, 0.0f);
                C[(size_t)(mbase + r) * 256 + n] = (OUT_T)v;
            }
        }
    }
}

// ---- Phase 6: pos_skip passthrough + zeros for the batch tail --------------
__global__ __launch_bounds__(256) void tail_kernel(
        const float* __restrict__ pos_skip, float* __restrict__ out, int out_size) {
    const int i = blockIdx.x * 256 + threadIdx.x;
    if (i < M_Q * 3) out[(size_t)M_Q * HDIM + i] = pos_skip[i];
    const int zbase = M_Q * HDIM + M_Q * 3;
    if (zbase + i < out_size) out[zbase + i] = 0.0f;
}

extern "C" void kernel_launch(void* const* d_in, const int* in_sizes, int n_in,
                              void* d_out, int out_size, void* d_ws, size_t ws_size,
                              hipStream_t stream) {
    (void)in_sizes; (void)n_in; (void)ws_size;
    const float* x        = (const float*)d_in[0];   // [4096,256]
    const float* pos      = (const float*)d_in[1];   // [4096,3]
    const float* x_skip   = (const float*)d_in[3];   // [16384,128]
    const float* pos_skip = (const float*)d_in[4];   // [16384,3]
    const float* W1       = (const float*)d_in[6];   // [384,256]
    const float* b1       = (const float*)d_in[7];   // [256]
    const float* W2       = (const float*)d_in[8];   // [256,256]
    const float* b2       = (const float*)d_in[9];   // [256]
    float* out = (float*)d_out;

    char* ws = (char*)d_ws;
    float*          cand_d = (float*)(ws);                    // M*96*4 = 6,291,456
    int*            cand_i = (int*)  (ws + 6291456);          // 6,291,456
    int*            idx    = (int*)  (ws + 12582912);         //   196,608
    float*          wn     = (float*)(ws + 12779520);         //   196,608
    __hip_bfloat16* h      = (__hip_bfloat16*)(ws + 12976128);// M*384*2 = 12,582,912
    __hip_bfloat16* hid    = (__hip_bfloat16*)(ws + 25559040);// M*256*2 =  8,388,608
    __hip_bfloat16* W1t    = (__hip_bfloat16*)(ws + 33947648);//   196,608
    __hip_bfloat16* W2t    = (__hip_bfloat16*)(ws + 34144256);//   131,072
                                                              // total ~34.3 MB

    knn_part_kernel <<<dim3(M_Q/256, NSPLIT), 256, 0, stream>>>(pos, pos_skip, cand_d, cand_i);
    knn_merge_kernel<<<M_Q*4/256, 256, 0, stream>>>(cand_d, cand_i, pos, pos_skip, idx, wn);
    interp_kernel   <<<M_Q, 192, 0, stream>>>(x, x_skip, idx, wn, h);
    convert_w_kernel<<<(C_H*HDIM + HDIM*HDIM)/256, 256, 0, stream>>>(W1, W2, W1t, W2t);
    gemm_bf16_kernel<true, C_H, __bf16><<<dim3(2, M_Q/64), 256, 0, stream>>>(
        (const __bf16*)h, (const __bf16*)W1t, b1, (__bf16*)hid);
    gemm_bf16_kernel<false, HDIM, float><<<dim3(2, M_Q/64), 256, 0, stream>>>(
        (const __bf16*)hid, (const __bf16*)W2t, b2, out);
    const int tail_n = (M_Q*3 > out_size - (M_Q*HDIM + M_Q*3)) ? M_Q*3 : out_size - (M_Q*HDIM + M_Q*3);
    tail_kernel     <<<(tail_n + 255)/256, 256, 0, stream>>>(pos_skip, out, out_size);
}

// Round 4
// 163.056 us; speedup vs baseline: 2.1934x; 1.9382x over previous
//
#include <hip/hip_runtime.h>
#include <hip/hip_bf16.h>

#define N_PTS  4096
#define M_Q    16384
#define C_IN   256
#define C_SKIP 128
#define C_H    384      // C_IN + C_SKIP
#define HDIM   256
#define NSPLIT 32
#define PTS_PER_SPLIT (N_PTS / NSPLIT)   // 128

typedef __bf16 bf16x8 __attribute__((ext_vector_type(8)));
typedef float  f32x4  __attribute__((ext_vector_type(4)));

__device__ __forceinline__ void insert3(float d, int j,
                                        float& b0, float& b1, float& b2,
                                        int& i0, int& i1, int& i2) {
    if (d < b2) {
        if (d < b1) {
            b2 = b1; i2 = i1;
            if (d < b0) { b1 = b0; i1 = i0; b0 = d; i0 = j; }
            else        { b1 = d;  i1 = j; }
        } else { b2 = d; i2 = j; }
    }
}

// ---- Phase 0: fused prep — W1/W2 convert+transpose, pos4 build -------------
__global__ __launch_bounds__(256) void prep_kernel(
        const float* __restrict__ W1, const float* __restrict__ W2,
        const float* __restrict__ pos,
        __hip_bfloat16* __restrict__ W1t, __hip_bfloat16* __restrict__ W2t,
        float4* __restrict__ pos4) {
    const int i = blockIdx.x * 256 + threadIdx.x;
    if (i < C_H * HDIM) {
        const int k = i / HDIM, n = i % HDIM;
        W1t[n * C_H + k] = __float2bfloat16(W1[i]);
    } else if (i < C_H * HDIM + HDIM * HDIM) {
        const int j = i - C_H * HDIM;
        const int k = j / HDIM, n = j % HDIM;
        W2t[n * HDIM + k] = __float2bfloat16(W2[j]);
    } else if (i < C_H * HDIM + HDIM * HDIM + N_PTS) {
        const int j = i - (C_H * HDIM + HDIM * HDIM);
        const float px = pos[j*3+0], py = pos[j*3+1], pz = pos[j*3+2];
        pos4[j] = make_float4(px, py, pz, px*px + py*py + pz*pz);
    }
}

// ---- Phase 1: partial kNN, 32-way split ------------------------------------
// Point stream via wave-uniform global reads (scalar s_load path) — NO LDS.
// Surrogate key d' = |p|^2 - 2 q.p (monotone-equivalent per query).
__global__ __launch_bounds__(256) void knn_part_kernel(
        const float4* __restrict__ pos4, const float* __restrict__ pos_skip,
        float* __restrict__ cand_d, int* __restrict__ cand_i) {
    const int s  = blockIdx.y;
    const int q  = blockIdx.x * 256 + threadIdx.x;
    const int j0 = s * PTS_PER_SPLIT;
    const float m2x = -2.0f * pos_skip[q*3+0];
    const float m2y = -2.0f * pos_skip[q*3+1];
    const float m2z = -2.0f * pos_skip[q*3+2];
    float b0 = 3e38f, b1 = 3e38f, b2 = 3e38f;
    int   i0 = 0, i1 = 0, i2 = 0;
    #pragma unroll 8
    for (int j = 0; j < PTS_PER_SPLIT; ++j) {
        const float4 p = pos4[j0 + j];      // uniform address -> SGPR broadcast
        const float d = fmaf(p.x, m2x, fmaf(p.y, m2y, fmaf(p.z, m2z, p.w)));
        const int  jj = j0 + j;
        const bool c2 = d < b2, c1 = d < b1, c0 = d < b0;
        b2 = c2 ? (c1 ? b1 : d) : b2;  i2 = c2 ? (c1 ? i1 : jj) : i2;
        b1 = c1 ? (c0 ? b0 : d) : b1;  i1 = c1 ? (c0 ? i0 : jj) : i1;
        b0 = c0 ? d : b0;              i0 = c0 ? jj : i0;
    }
    // SoA rank-major layout: cand_d[r][s][q] -> 6 fully-coalesced dword stores
    const int base = s * M_Q + q;
    cand_d[0*NSPLIT*M_Q + base] = b0;
    cand_d[1*NSPLIT*M_Q + base] = b1;
    cand_d[2*NSPLIT*M_Q + base] = b2;
    cand_i[0*NSPLIT*M_Q + base] = i0;
    cand_i[1*NSPLIT*M_Q + base] = i1;
    cand_i[2*NSPLIT*M_Q + base] = i2;
}

// ---- Phase 2: merge 96 candidates (4 lanes/query) -> top-3 + weights -------
__global__ __launch_bounds__(256) void knn_merge_kernel(
        const float* __restrict__ cand_d, const int* __restrict__ cand_i,
        const float* __restrict__ pos, const float* __restrict__ pos_skip,
        int* __restrict__ idx, float* __restrict__ wn) {
    const int tid = blockIdx.x * 256 + threadIdx.x;
    const int q = tid >> 2;
    const int l = tid & 3;             // 4 lanes per query, lane l owns 8 splits
    float b0 = 3e38f, b1 = 3e38f, b2 = 3e38f;
    int   i0 = 0, i1 = 0, i2 = 0;
    const int SM = NSPLIT * M_Q;
    #pragma unroll
    for (int u = 0; u < NSPLIT/4; ++u) {
        const int s = l * (NSPLIT/4) + u;   // ascending split = ascending index, tie-break safe
        const int base = s * M_Q + q;
        const float d0 = cand_d[0*SM + base], d1 = cand_d[1*SM + base], d2c = cand_d[2*SM + base];
        const int   j0 = cand_i[0*SM + base], j1 = cand_i[1*SM + base], j2c = cand_i[2*SM + base];
        insert3(d0, j0,  b0,b1,b2, i0,i1,i2);
        insert3(d1, j1,  b0,b1,b2, i0,i1,i2);
        insert3(d2c, j2c, b0,b1,b2, i0,i1,i2);
    }
    // cross-lane merge; lower lane's triple is the base so ties keep lowest index
    #pragma unroll
    for (int m = 1; m <= 2; m <<= 1) {
        const float nb0 = __shfl_xor(b0, m), nb1 = __shfl_xor(b1, m), nb2 = __shfl_xor(b2, m);
        const int   ni0 = __shfl_xor(i0, m), ni1 = __shfl_xor(i1, m), ni2 = __shfl_xor(i2, m);
        const bool upper = (l & m) != 0;
        float e0 = upper ? b0 : nb0, e1 = upper ? b1 : nb1, e2 = upper ? b2 : nb2;
        int   f0 = upper ? i0 : ni0, f1 = upper ? i1 : ni1, f2 = upper ? i2 : ni2;
        if (upper) { b0 = nb0; b1 = nb1; b2 = nb2; i0 = ni0; i1 = ni1; i2 = ni2; }
        insert3(e0, f0, b0,b1,b2, i0,i1,i2);
        insert3(e1, f1, b0,b1,b2, i0,i1,i2);
        insert3(e2, f2, b0,b1,b2, i0,i1,i2);
    }
    if (l == 0) {
        const float qx = pos_skip[q*3+0], qy = pos_skip[q*3+1], qz = pos_skip[q*3+2];
        float w[3]; int ii[3] = {i0, i1, i2};
        #pragma unroll
        for (int r = 0; r < 3; ++r) {
            const float dx = qx - pos[ii[r]*3+0];
            const float dy = qy - pos[ii[r]*3+1];
            const float dz = qz - pos[ii[r]*3+2];
            const float d2 = dx*dx + dy*dy + dz*dz;   // exact recompute, like reference d2k
            w[r] = 1.0f / fmaxf(d2, 1e-16f);
        }
        const float inv = 1.0f / (w[0] + w[1] + w[2]);
        idx[q*3+0] = ii[0]; idx[q*3+1] = ii[1]; idx[q*3+2] = ii[2];
        wn[q*3+0] = w[0]*inv; wn[q*3+1] = w[1]*inv; wn[q*3+2] = w[2]*inv;
    }
}

// ---- Phase 3: gather-interpolate + concat skip -> h[M x 384] (bf16) --------
__global__ __launch_bounds__(192) void interp_kernel(
        const float* __restrict__ x, const float* __restrict__ x_skip,
        const int* __restrict__ idx, const float* __restrict__ wn,
        __hip_bfloat16* __restrict__ h) {
    const int q = blockIdx.x;
    const int t = threadIdx.x;
    if (t < 128) {
        const int c = t * 2;
        const int   i0 = idx[q*3+0], i1 = idx[q*3+1], i2 = idx[q*3+2];
        const float w0 = wn[q*3+0],  w1 = wn[q*3+1],  w2 = wn[q*3+2];
        const float2 v0 = *(const float2*)(x + (size_t)i0 * C_IN + c);
        const float2 v1 = *(const float2*)(x + (size_t)i1 * C_IN + c);
        const float2 v2 = *(const float2*)(x + (size_t)i2 * C_IN + c);
        __hip_bfloat162 o;
        o.x = __float2bfloat16(w0*v0.x + w1*v1.x + w2*v2.x);
        o.y = __float2bfloat16(w0*v0.y + w1*v1.y + w2*v2.y);
        *(__hip_bfloat162*)(h + (size_t)q * C_H + c) = o;
    } else {
        const int c = (t - 128) * 2;
        const float2 v = *(const float2*)(x_skip + (size_t)q * C_SKIP + c);
        __hip_bfloat162 o;
        o.x = __float2bfloat16(v.x);
        o.y = __float2bfloat16(v.y);
        *(__hip_bfloat162*)(h + (size_t)q * C_H + C_IN + c) = o;
    }
}

// ---- Phase 4/5: bf16 MFMA GEMM. C[M x 256] = A[M x K] @ Bt^T + bias --------
// A[M x K] bf16 row-major, Bt[256 x K] bf16 row-major (pre-transposed weights).
// Block 256 thr = 4 waves (2x2), tile BM=64 x BN=128, BK=32.
template<bool RELU, int KDIM, typename OUT_T>
__global__ __launch_bounds__(256) void gemm_bf16_kernel(
        const __bf16* __restrict__ A, const __bf16* __restrict__ Bt,
        const float* __restrict__ bias, OUT_T* __restrict__ C) {
    __shared__ __bf16 As[64][40];    // pad 32->40 (80B stride, 16B aligned)
    __shared__ __bf16 Bs[128][40];
    const int t    = threadIdx.x;
    const int wave = t >> 6;
    const int lane = t & 63;
    const int ln = lane & 15, kq = lane >> 4;
    const int m0 = blockIdx.y * 64;
    const int n0 = blockIdx.x * 128;
    const int wm = (wave >> 1) * 32;   // 2 m-tiles of 16
    const int wn = (wave & 1) * 64;    // 4 n-tiles of 16

    const int rA = t >> 1, cA = (t & 1) * 16;   // 16 bf16 (= 32 B) per thread

    f32x4 acc[2][4] = {};

    for (int k0 = 0; k0 < KDIM; k0 += 32) {
        int4 aval0, aval1;
        if (t < 128) {
            aval0 = *(const int4*)(A + (size_t)(m0 + rA) * KDIM + k0 + cA);
            aval1 = *(const int4*)(A + (size_t)(m0 + rA) * KDIM + k0 + cA + 8);
        }
        const int4 bval0 = *(const int4*)(Bt + (size_t)(n0 + rA) * KDIM + k0 + cA);
        const int4 bval1 = *(const int4*)(Bt + (size_t)(n0 + rA) * KDIM + k0 + cA + 8);
        __syncthreads();   // previous iteration's LDS reads complete
        if (t < 128) {
            *(int4*)&As[rA][cA]     = aval0;
            *(int4*)&As[rA][cA + 8] = aval1;
        }
        *(int4*)&Bs[rA][cA]     = bval0;
        *(int4*)&Bs[rA][cA + 8] = bval1;
        __syncthreads();
        bf16x8 af[2], bf[4];
        #pragma unroll
        for (int mt = 0; mt < 2; ++mt)
            af[mt] = *(const bf16x8*)&As[wm + mt*16 + ln][kq*8];
        #pragma unroll
        for (int nt = 0; nt < 4; ++nt)
            bf[nt] = *(const bf16x8*)&Bs[wn + nt*16 + ln][kq*8];
        #pragma unroll
        for (int mt = 0; mt < 2; ++mt)
            #pragma unroll
            for (int nt = 0; nt < 4; ++nt)
                acc[mt][nt] = __builtin_amdgcn_mfma_f32_16x16x32_bf16(
                                  af[mt], bf[nt], acc[mt][nt], 0, 0, 0);
    }

    // epilogue: C/D layout col=lane&15, row=(lane>>4)*4+reg
    #pragma unroll
    for (int nt = 0; nt < 4; ++nt) {
        const int n = n0 + wn + nt*16 + ln;
        const float bv = bias[n];
        #pragma unroll
        for (int mt = 0; mt < 2; ++mt) {
            const int mbase = m0 + wm + mt*16 + kq*4;
            #pragma unroll
            for (int r = 0; r < 4; ++r) {
                float v = acc[mt][nt][r] + bv;
                if (RELU) v = fmaxf(v, 0.0f);
                C[(size_t)(mbase + r) * 256 + n] = (OUT_T)v;
            }
        }
    }
}

// ---- Phase 6: pos_skip passthrough + zeros for the batch tail --------------
__global__ __launch_bounds__(256) void tail_kernel(
        const float* __restrict__ pos_skip, float* __restrict__ out, int out_size) {
    const int i = blockIdx.x * 256 + threadIdx.x;
    if (i < M_Q * 3) out[(size_t)M_Q * HDIM + i] = pos_skip[i];
    const int zbase = M_Q * HDIM + M_Q * 3;
    if (zbase + i < out_size) out[zbase + i] = 0.0f;
}

extern "C" void kernel_launch(void* const* d_in, const int* in_sizes, int n_in,
                              void* d_out, int out_size, void* d_ws, size_t ws_size,
                              hipStream_t stream) {
    (void)in_sizes; (void)n_in; (void)ws_size;
    const float* x        = (const float*)d_in[0];   // [4096,256]
    const float* pos      = (const float*)d_in[1];   // [4096,3]
    const float* x_skip   = (const float*)d_in[3];   // [16384,128]
    const float* pos_skip = (const float*)d_in[4];   // [16384,3]
    const float* W1       = (const float*)d_in[6];   // [384,256]
    const float* b1       = (const float*)d_in[7];   // [256]
    const float* W2       = (const float*)d_in[8];   // [256,256]
    const float* b2       = (const float*)d_in[9];   // [256]
    float* out = (float*)d_out;

    char* ws = (char*)d_ws;
    float*          cand_d = (float*)(ws);                    // M*96*4 = 6,291,456
    int*            cand_i = (int*)  (ws + 6291456);          // 6,291,456
    int*            idx    = (int*)  (ws + 12582912);         //   196,608
    float*          wn     = (float*)(ws + 12779520);         //   196,608
    __hip_bfloat16* h      = (__hip_bfloat16*)(ws + 12976128);// M*384*2 = 12,582,912
    __hip_bfloat16* hid    = (__hip_bfloat16*)(ws + 25559040);// M*256*2 =  8,388,608
    __hip_bfloat16* W1t    = (__hip_bfloat16*)(ws + 33947648);//   196,608
    __hip_bfloat16* W2t    = (__hip_bfloat16*)(ws + 34144256);//   131,072
    float4*         pos4   = (float4*)(ws + 34275328);        //    65,536
                                                              // total ~34.3 MB

    prep_kernel     <<<(C_H*HDIM + HDIM*HDIM + N_PTS + 255)/256, 256, 0, stream>>>(
        W1, W2, pos, W1t, W2t, pos4);
    knn_part_kernel <<<dim3(M_Q/256, NSPLIT), 256, 0, stream>>>(pos4, pos_skip, cand_d, cand_i);
    knn_merge_kernel<<<M_Q*4/256, 256, 0, stream>>>(cand_d, cand_i, pos, pos_skip, idx, wn);
    interp_kernel   <<<M_Q, 192, 0, stream>>>(x, x_skip, idx, wn, h);
    gemm_bf16_kernel<true, C_H, __bf16><<<dim3(2, M_Q/64), 256, 0, stream>>>(
        (const __bf16*)h, (const __bf16*)W1t, b1, (__bf16*)hid);
    gemm_bf16_kernel<false, HDIM, float><<<dim3(2, M_Q/64), 256, 0, stream>>>(
        (const __bf16*)hid, (const __bf16*)W2t, b2, out);
    const int tail_n = (M_Q*3 > out_size - (M_Q*HDIM + M_Q*3)) ? M_Q*3 : out_size - (M_Q*HDIM + M_Q*3);
    tail_kernel     <<<(tail_n + 255)/256, 256, 0, stream>>>(pos_skip, out, out_size);
}